// Round 9
// baseline (489.577 us; speedup 1.0000x reference)
//
#include <hip/hip_runtime.h>
#include <hip/hip_bf16.h>

typedef __attribute__((ext_vector_type(8))) short short8;
typedef __attribute__((ext_vector_type(4))) short short4_t;
typedef __attribute__((ext_vector_type(4))) float f32x4;

constexpr int MBS = 16, HD = 64, NMB = 256;

#define MFMA32(a, b, c) __builtin_amdgcn_mfma_f32_16x16x32_bf16(a, b, c, 0, 0, 0)
#define TR_READ(dst, addr, IMM) \
    asm volatile("ds_read_b64_tr_b16 %0, %1 offset:" IMM : "=&v"(dst) : "v"(addr) : "memory")

union U4S8 { unsigned u[4]; short8 s; };
union U2S4 { unsigned u[2]; short4_t s; };
union FI { float f; int i; };

__device__ inline unsigned pkbf(float a, float b) {
    union { __hip_bfloat162 h; unsigned u; } c;
    c.h = __float22bfloat162_rn(make_float2(a, b));
    return c.u;
}
__device__ inline short8 cmb(short4_t a, short4_t b) {
    short8 r;
    r[0]=a[0]; r[1]=a[1]; r[2]=a[2]; r[3]=a[3];
    r[4]=b[0]; r[5]=b[1]; r[6]=b[2]; r[7]=b[3];
    return r;
}
// all-VALU 16-lane sum reduce: quad_perm xor1, xor2, then row_ror 4, 8
__device__ inline float dpp16(float x) {
    FI v; v.f = x; FI t;
    t.i = __builtin_amdgcn_update_dpp(0, v.i, 0xB1, 0xf, 0xf, true);  v.f += t.f;
    t.i = __builtin_amdgcn_update_dpp(0, v.i, 0x4E, 0xf, 0xf, true);  v.f += t.f;
    t.i = __builtin_amdgcn_update_dpp(0, v.i, 0x124, 0xf, 0xf, true); v.f += t.f;
    t.i = __builtin_amdgcn_update_dpp(0, v.i, 0x128, 0xf, 0xf, true); v.f += t.f;
    return v.f;
}
// raw barrier: LDS writes visible, global loads stay in flight
__device__ inline void bar() {
    __builtin_amdgcn_sched_barrier(0);
    asm volatile("s_waitcnt lgkmcnt(0)" ::: "memory");
    __builtin_amdgcn_s_barrier();
    __builtin_amdgcn_sched_barrier(0);
}

struct __align__(16) ChainSM {
    short sWt[64 * 72];    // W^T bf16 [n][k], stride 72           9216 B
    short bxk[16 * 72];    //                                       2304 B
    short bxq[16 * 72];    //                                       2304 B
    short sGt[1024];       // g tiled, jblk 0..3 (live half)        2048 B
    short sXKe[1024];      // -le*xk tiled, jblk 0..3               2048 B
    short sE[16 * 40];     // -E [r][j], j zero-padded to 32        1280 B
    float sZ1[16 * 68];    //                                       4352 B
    float sZb[16 * 68];    //                                       4352 B
    float sAttn[16 * 20];  //                                       1280 B
    float sEta[2][256];    // parity-buffered                       2048 B
};                         // total 31232 B

__global__ __launch_bounds__(512) void ttt_scan(
    const float* __restrict__ gXQ, const float* __restrict__ gXK,
    const float* __restrict__ gXV, const float* __restrict__ gETA,
    const float* __restrict__ gW1, const float* __restrict__ gB1,
    const float* __restrict__ gLNW, const float* __restrict__ gLNB,
    float* __restrict__ gOUT)
{
    __shared__ ChainSM ch[2];          // 62464 B
    __shared__ __align__(16) short sZERO[1024];  // shared hi-jblk zeros, 2048 B

    const int gt = threadIdx.x;
    const int cw = gt >> 8;            // chain within WG
    const int t  = gt & 255;           // chain-local tid
    ChainSM& C = ch[cw];

    const int s  = t >> 4;
    const int dt = t & 15;
    const int lane = t & 63;
    const int w  = (t >> 6) & 3;
    const int gq = lane >> 4;
    const int lc = lane & 15;
    const int bh = blockIdx.x * 2 + cw, b = bh >> 3, h = bh & 7;

    const float* xqg = gXQ + (size_t)bh * (NMB * MBS * HD);
    const float* xkg = gXK + (size_t)bh * (NMB * MBS * HD);
    const float* xvg = gXV + (size_t)bh * (NMB * MBS * HD);
    const float* etg = gETA + (size_t)bh * (NMB * MBS * MBS);

    for (int i = gt; i < 1024; i += 512) sZERO[i] = 0;
    for (int i = t; i < 16 * 40; i += 256) C.sE[i] = 0;

    // W state: wave w owns rows [16w,16w+16) as 4 C-fragments + bf16 mirror
    f32x4 Wacc[4];
#pragma unroll
    for (int ct = 0; ct < 4; ++ct) {
#pragma unroll
        for (int r = 0; r < 4; ++r)
            Wacc[ct][r] = gW1[h * 4096 + (16 * w + 4 * gq + r) * 64 + 16 * ct + lc];
        U2S4 wp;
        wp.u[0] = pkbf(Wacc[ct][0], Wacc[ct][1]);
        wp.u[1] = pkbf(Wacc[ct][2], Wacc[ct][3]);
        *(short4_t*)&C.sWt[(16 * ct + lc) * 72 + 16 * w + 4 * gq] = wp.s;
    }
    // b1 state: register, wave w owns col 16w+lc
    float b1v = gB1[h * 64 + 16 * w + lc];

    const float4 gam = *(const float4*)&gLNW[h * 64 + dt * 4];
    const float4 bet = *(const float4*)&gLNB[h * 64 + dt * 4];
    const float ga[4] = {gam.x, gam.y, gam.z, gam.w};
    const float ba[4] = {bet.x, bet.y, bet.z, bet.w};
    float c1a[4], gba[4];
    float sc1 = 0.f;
#pragma unroll
    for (int c = 0; c < 4; ++c) {
        c1a[c] = ga[c] * ga[c];
        gba[c] = ga[c] * ba[c];
        sc1 += c1a[c];
    }
    sc1 = dpp16(sc1);

    const int ecol = (gq < 2) ? 8 * gq : 0;   // aL source columns (clamped)

    // ---- load + stage minibatch 0 ----
    float4 pq = *(const float4*)&xqg[t * 4];
    float4 pk = *(const float4*)&xkg[t * 4];
    float4 pv = *(const float4*)&xvg[t * 4];
    float4 pe = make_float4(0.f, 0.f, 0.f, 0.f);
    if (t < 64) pe = *(const float4*)&etg[t * 4];

    { U2S4 u_; u_.u[0]=pkbf(pk.x,pk.y); u_.u[1]=pkbf(pk.z,pk.w);
      *(short4_t*)&C.bxk[s * 72 + dt * 4] = u_.s; }
    { U2S4 u_; u_.u[0]=pkbf(pq.x,pq.y); u_.u[1]=pkbf(pq.z,pq.w);
      *(short4_t*)&C.bxq[s * 72 + dt * 4] = u_.s; }
    if (t < 64) *(float4*)&C.sEta[0][t * 4] = pe;
    float t2c[4];
    {
        const float pva[4] = {pv.x, pv.y, pv.z, pv.w};
        const float pka_[4] = {pk.x, pk.y, pk.z, pk.w};
#pragma unroll
        for (int c = 0; c < 4; ++c)
            t2c[c] = fmaf(-ga[c], pva[c] - pka_[c], gba[c]);
    }
    float4 pkc = pk;        // xk(m) for THREAD1's sXKe
    float4 pq_out = pq;     // xq(m) for THREAD2(m)
    float4 pq_prev_out;     // xq(m-1) for deferred THREAD2

    __syncthreads();

#pragma unroll 1
    for (int m = 0; m < NMB; ++m) {
        const int p = m & 1;

        // ======== PHASE A: MFMA1 (+ deferred THREAD2 of m-1; prefetch m+1) ========
        if (m + 1 < NMB) {
            const size_t o = (size_t)(m + 1) * (MBS * HD) + t * 4;
            pq = *(const float4*)&xqg[o];
            pk = *(const float4*)&xkg[o];
            pv = *(const float4*)&xvg[o];
            if (t < 64) pe = *(const float4*)&etg[(size_t)(m + 1) * (MBS * MBS) + t * 4];
        }

        f32x4 z1a; z1a[0]=b1v; z1a[1]=b1v; z1a[2]=b1v; z1a[3]=b1v;
        f32x4 zqa = z1a;
        const short8 ak0 = *(const short8*)&C.bxk[lc * 72 + gq * 8];
        const short8 ak1 = *(const short8*)&C.bxk[lc * 72 + gq * 8 + 32];
        const short8 aq0 = *(const short8*)&C.bxq[lc * 72 + gq * 8];
        const short8 aq1 = *(const short8*)&C.bxq[lc * 72 + gq * 8 + 32];
        const short8 bw0 = *(const short8*)&C.sWt[(16 * w + lc) * 72 + gq * 8];
        const short8 bw1 = *(const short8*)&C.sWt[(16 * w + lc) * 72 + gq * 8 + 32];
        z1a = MFMA32(ak0, bw0, z1a); z1a = MFMA32(ak1, bw1, z1a);
        zqa = MFMA32(aq0, bw0, zqa); zqa = MFMA32(aq1, bw1, zqa);
#pragma unroll
        for (int r = 0; r < 4; ++r) C.sZ1[(4 * gq + r) * 68 + 16 * w + lc] = z1a[r];
        if (w == 3) {
            f32x4 zz; zz[0]=0.f; zz[1]=0.f; zz[2]=0.f; zz[3]=0.f;
            zz = MFMA32(aq0, ak0, zz); zz = MFMA32(aq1, ak1, zz);
#pragma unroll
            for (int r = 0; r < 4; ++r) C.sAttn[(4 * gq + r) * 20 + lc] = zz[r];
        }

        // deferred THREAD2 for step m-1 (off the W-recurrence chain)
        if (m > 0) {
            f32x4 zbr = *(f32x4*)&C.sZb[s * 68 + dt * 4];
            float T1 = 0.f, T2 = 0.f;
#pragma unroll
            for (int c = 0; c < 4; ++c) { T1 += zbr[c]; T2 = fmaf(zbr[c], zbr[c], T2); }
            T1 = dpp16(T1); T2 = dpp16(T2);
            const float mu2   = T1 * (1.f / 64.f);
            const float rstd2 = rsqrtf(T2 * (1.f / 64.f) - mu2 * mu2 + 1e-6f);
            const float pqa[4] = {pq_prev_out.x, pq_prev_out.y, pq_prev_out.z, pq_prev_out.w};
            float o[4];
#pragma unroll
            for (int c = 0; c < 4; ++c)
                o[c] = pqa[c] + fmaf(ga[c], (zbr[c] - mu2) * rstd2, ba[c]);
            const size_t oi = ((size_t)b * 4096 + (size_t)(m - 1) * 16 + s) * 512 + h * 64 + dt * 4;
            *(float4*)&gOUT[oi] = make_float4(o[0], o[1], o[2], o[3]);
        }
        bar();   // (C)

        // ======== PHASE B: THREAD1 — LN-bwd (DPP 6-sum) -> g ; stage g^T, xke^T, E ====
        f32x4 z = *(f32x4*)&C.sZ1[s * 68 + dt * 4];
        float S1=0.f,S2=0.f,S3=0.f,S4=0.f,S5=0.f,S6=0.f;
#pragma unroll
        for (int c = 0; c < 4; ++c) {
            const float zc = z[c], c1z = c1a[c] * zc, t2 = t2c[c];
            S1 += zc;  S2 = fmaf(zc, zc, S2);
            S3 += c1z; S4 = fmaf(c1z, zc, S4);
            S5 += t2;  S6 = fmaf(t2, zc, S6);
        }
        S1 = dpp16(S1); S2 = dpp16(S2); S3 = dpp16(S3);
        S4 = dpp16(S4); S5 = dpp16(S5); S6 = dpp16(S6);
        const float mu   = S1 * (1.f / 64.f);
        const float rstd = rsqrtf(S2 * (1.f / 64.f) - mu * mu + 1e-6f);
        const float r1 = rstd * (S3 - mu * sc1) + S5;
        const float r2 = rstd * rstd * (S4 - 2.f * mu * S3 + mu * mu * sc1)
                       + rstd * (S6 - mu * S5);
        const float cf = rstd * (1.f / 64.f);
        float g[4];
#pragma unroll
        for (int c = 0; c < 4; ++c) {
            const float xh = (z[c] - mu) * rstd;
            const float gx = fmaf(c1a[c], xh, t2c[c]);
            g[c] = (fmaf(64.f, gx, -r1) - xh * r2) * cf;
        }

        const float le = C.sEta[p][240 + s];
        const int tb = (s >> 2) * 256 + (dt >> 2) * 64 + (s & 3) * 16 + (dt & 3) * 4;
        { U2S4 gp; gp.u[0]=pkbf(g[0],g[1]); gp.u[1]=pkbf(g[2],g[3]);
          *(short4_t*)&C.sGt[tb] = gp.s; }
        { U2S4 kp; kp.u[0]=pkbf(-le*pkc.x,-le*pkc.y); kp.u[1]=pkbf(-le*pkc.z,-le*pkc.w);
          *(short4_t*)&C.sXKe[tb] = kp.s; }

        // E = tril*eta*(1+Attn); store -E
        if (dt < 4) {
            f32x4 at = *(f32x4*)&C.sAttn[s * 20 + dt * 4];
            f32x4 ev = *(f32x4*)&C.sEta[p][s * 16 + dt * 4];
            U2S4 ep;
            float x[4];
#pragma unroll
            for (int c = 0; c < 4; ++c) {
                const int cc = 4 * dt + c;
                x[c] = (cc <= s) ? -ev[c] * (1.f + at[c]) : 0.f;
            }
            ep.u[0] = pkbf(x[0], x[1]); ep.u[1] = pkbf(x[2], x[3]);
            *(short4_t*)&C.sE[s * 40 + 4 * dt] = ep.s;
        }
        bar();   // (D)

        // ======== PHASE C: MFMA2 (Z1_bar, W, b1) + STAGE(m+1) ========
        // hi-jblk (gq>=2) reads route to the shared zero buffer
        const unsigned gbase = (gq < 2)
            ? ((unsigned)(size_t)&C.sGt[0] + 1024u * gq + 8u * lc)
            : ((unsigned)(size_t)&sZERO[0] + 8u * lc);
        const unsigned ebase = gbase + 128u * (unsigned)w;
        const unsigned kbase = ((gq < 2)
            ? ((unsigned)(size_t)&C.sXKe[0] + 1024u * gq)
            : ((unsigned)(size_t)&sZERO[0]))
            + 8u * lc + 128u * (unsigned)w;
        short4_t elo, ehi, al, ah;
        short4_t bl0, bh0, bl1, bh1, bl2, bh2, bl3, bh3;
        TR_READ(elo, ebase, "0");   TR_READ(ehi, ebase, "512");
        TR_READ(al,  kbase, "0");   TR_READ(ah,  kbase, "512");
        TR_READ(bl0, gbase, "0");   TR_READ(bh0, gbase, "512");
        TR_READ(bl1, gbase, "128"); TR_READ(bh1, gbase, "640");
        TR_READ(bl2, gbase, "256"); TR_READ(bh2, gbase, "768");
        TR_READ(bl3, gbase, "384"); TR_READ(bh3, gbase, "896");
        const short8 aE = *(const short8*)&C.sE[lc * 40 + gq * 8];
        // aL: A[row][k] = -le[k] (k<16; zero for gq>=2), from current step's eta
        const f32x4 le0 = *(const f32x4*)&C.sEta[p][240 + ecol];
        const f32x4 le1 = *(const f32x4*)&C.sEta[p][244 + ecol];
        U4S8 aL;
        {
            const float lv[8] = {le0[0], le0[1], le0[2], le0[3], le1[0], le1[1], le1[2], le1[3]};
#pragma unroll
            for (int pp = 0; pp < 4; ++pp) {
                const float y0 = (gq < 2) ? -lv[2 * pp] : 0.f;
                const float y1 = (gq < 2) ? -lv[2 * pp + 1] : 0.f;
                aL.u[pp] = pkbf(y0, y1);
            }
        }
        asm volatile("s_waitcnt lgkmcnt(0)" ::: "memory");
        __builtin_amdgcn_sched_barrier(0);

        const short8 bgw = cmb(elo, ehi);
        f32x4 zb = MFMA32(aE, bgw, zqa);
#pragma unroll
        for (int r = 0; r < 4; ++r) C.sZb[(4 * gq + r) * 68 + 16 * w + lc] = zb[r];

        const short8 aK = cmb(al, ah);
        Wacc[0] = MFMA32(aK, cmb(bl0, bh0), Wacc[0]);
        Wacc[1] = MFMA32(aK, cmb(bl1, bh1), Wacc[1]);
        Wacc[2] = MFMA32(aK, cmb(bl2, bh2), Wacc[2]);
        Wacc[3] = MFMA32(aK, cmb(bl3, bh3), Wacc[3]);
        // b1 update: d0 = (-le) @ g  (same B-frag as zb)
        {
            f32x4 d0; d0[0]=0.f; d0[1]=0.f; d0[2]=0.f; d0[3]=0.f;
            d0 = MFMA32(aL.s, bgw, d0);
            b1v += d0[0];
        }
#pragma unroll
        for (int ct = 0; ct < 4; ++ct) {
            U2S4 wp;
            wp.u[0] = pkbf(Wacc[ct][0], Wacc[ct][1]);
            wp.u[1] = pkbf(Wacc[ct][2], Wacc[ct][3]);
            *(short4_t*)&C.sWt[(16 * ct + lc) * 72 + 16 * w + 4 * gq] = wp.s;
        }

        // STAGE(m+1): bxk/bxq/sEta[p^1]/t2 from prefetched regs (buffers dead since bar D)
        if (m + 1 < NMB) {
            { U2S4 u_; u_.u[0]=pkbf(pk.x,pk.y); u_.u[1]=pkbf(pk.z,pk.w);
              *(short4_t*)&C.bxk[s * 72 + dt * 4] = u_.s; }
            { U2S4 u_; u_.u[0]=pkbf(pq.x,pq.y); u_.u[1]=pkbf(pq.z,pq.w);
              *(short4_t*)&C.bxq[s * 72 + dt * 4] = u_.s; }
            if (t < 64) *(float4*)&C.sEta[p ^ 1][t * 4] = pe;
#pragma unroll
            for (int c = 0; c < 4; ++c) {
                const float pva[4] = {pv.x, pv.y, pv.z, pv.w};
                const float pka_[4] = {pk.x, pk.y, pk.z, pk.w};
                t2c[c] = fmaf(-ga[c], pva[c] - pka_[c], gba[c]);
            }
            pkc = pk;
        }
        pq_prev_out = pq_out;
        pq_out = pq;
        bar();   // (E)
    }

    // epilogue: deferred THREAD2 for m = NMB-1
    {
        f32x4 zbr = *(f32x4*)&C.sZb[s * 68 + dt * 4];
        float T1 = 0.f, T2 = 0.f;
#pragma unroll
        for (int c = 0; c < 4; ++c) { T1 += zbr[c]; T2 = fmaf(zbr[c], zbr[c], T2); }
        T1 = dpp16(T1); T2 = dpp16(T2);
        const float mu2   = T1 * (1.f / 64.f);
        const float rstd2 = rsqrtf(T2 * (1.f / 64.f) - mu2 * mu2 + 1e-6f);
        const float pqa[4] = {pq_prev_out.x, pq_prev_out.y, pq_prev_out.z, pq_prev_out.w};
        float o[4];
#pragma unroll
        for (int c = 0; c < 4; ++c)
            o[c] = pqa[c] + fmaf(ga[c], (zbr[c] - mu2) * rstd2, ba[c]);
        const size_t oi = ((size_t)b * 4096 + (size_t)(NMB - 1) * 16 + s) * 512 + h * 64 + dt * 4;
        *(float4*)&gOUT[oi] = make_float4(o[0], o[1], o[2], o[3]);
    }
}

extern "C" void kernel_launch(void* const* d_in, const int* in_sizes, int n_in,
                              void* d_out, int out_size, void* d_ws, size_t ws_size,
                              hipStream_t stream) {
    const float* XQ  = (const float*)d_in[0];
    const float* XK  = (const float*)d_in[1];
    const float* XV  = (const float*)d_in[2];
    const float* ETA = (const float*)d_in[3];
    const float* W1  = (const float*)d_in[4];
    const float* B1  = (const float*)d_in[5];
    const float* LNW = (const float*)d_in[6];
    const float* LNB = (const float*)d_in[7];
    float* OUT = (float*)d_out;

    const int n_chains = in_sizes[0] / (NMB * MBS * HD);   // B*nh = 64
    ttt_scan<<<n_chains / 2, 512, 0, stream>>>(XQ, XK, XV, ETA, W1, B1, LNW, LNB, OUT);
}

// Round 10
// 374.745 us; speedup vs baseline: 1.3064x; 1.3064x over previous
//
#include <hip/hip_runtime.h>
#include <hip/hip_bf16.h>

typedef __attribute__((ext_vector_type(8))) short short8;
typedef __attribute__((ext_vector_type(4))) short short4_t;
typedef __attribute__((ext_vector_type(4))) float f32x4;

constexpr int MBS = 16, HD = 64, NMB = 256;

#define MFMA32(a, b, c) __builtin_amdgcn_mfma_f32_16x16x32_bf16(a, b, c, 0, 0, 0)

#if __has_builtin(__builtin_amdgcn_mfma_f32_16x16x16bf16_1k)
#define MFMA16(a, b, c) __builtin_amdgcn_mfma_f32_16x16x16bf16_1k(a, b, c, 0, 0, 0)
#else
__device__ inline f32x4 mfma16_asm(short4_t a, short4_t b, f32x4 c) {
    asm volatile("v_mfma_f32_16x16x16_bf16 %0, %1, %2, %0\n\ts_nop 7\n\ts_nop 7"
                 : "+v"(c) : "v"(a), "v"(b));
    return c;
}
#define MFMA16(a, b, c) mfma16_asm(a, b, c)
#endif

#define TR_READ(dst, addr, IMM) \
    asm volatile("ds_read_b64_tr_b16 %0, %1 offset:" IMM : "=&v"(dst) : "v"(addr) : "memory")

union U2S4 { unsigned u[2]; short4_t s; };
union FI { float f; int i; };

__device__ inline unsigned pkbf(float a, float b) {
    union { __hip_bfloat162 h; unsigned u; } c;
    c.h = __float22bfloat162_rn(make_float2(a, b));
    return c.u;
}
__device__ inline short bf16s(float x) { return (short)(pkbf(x, 0.f) & 0xffffu); }
// all-VALU 16-lane sum reduce: quad_perm xor1, xor2, then row_ror 4, 8
__device__ inline float dpp16(float x) {
    FI v; v.f = x; FI t;
    t.i = __builtin_amdgcn_update_dpp(0, v.i, 0xB1, 0xf, 0xf, true);  v.f += t.f;
    t.i = __builtin_amdgcn_update_dpp(0, v.i, 0x4E, 0xf, 0xf, true);  v.f += t.f;
    t.i = __builtin_amdgcn_update_dpp(0, v.i, 0x124, 0xf, 0xf, true); v.f += t.f;
    t.i = __builtin_amdgcn_update_dpp(0, v.i, 0x128, 0xf, 0xf, true); v.f += t.f;
    return v.f;
}
// raw barrier: LDS writes visible, global loads stay in flight
__device__ inline void bar() {
    __builtin_amdgcn_sched_barrier(0);
    asm volatile("s_waitcnt lgkmcnt(0)" ::: "memory");
    __builtin_amdgcn_s_barrier();
    __builtin_amdgcn_sched_barrier(0);
}

__global__ __launch_bounds__(256) void ttt_scan(
    const float* __restrict__ gXQ, const float* __restrict__ gXK,
    const float* __restrict__ gXV, const float* __restrict__ gETA,
    const float* __restrict__ gW1, const float* __restrict__ gB1,
    const float* __restrict__ gLNW, const float* __restrict__ gLNB,
    float* __restrict__ gOUT)
{
    __shared__ __align__(16) short sWt[64 * 72];   // W^T bf16 [n][k], stride 72
    __shared__ __align__(16) short bxk[16 * 72];
    __shared__ __align__(16) short bxq[16 * 72];
    __shared__ __align__(16) short sGt[1024];      // g, K=16 4x16 tiles [jblk][nblk]
    __shared__ __align__(16) short sXKe[1024];     // -le*xk, same tiling
    __shared__ __align__(16) short sE[16 * 20];    // -E [r][j], row stride 20
    __shared__ __align__(16) float sZ1[16 * 68];
    __shared__ __align__(16) float sZb[16 * 68];
    __shared__ __align__(16) float sEta[2][256];   // parity-buffered

    const int t  = threadIdx.x;
    const int s  = t >> 4;
    const int dt = t & 15;
    const int lane = t & 63;
    const int w  = t >> 6;
    const int gq = lane >> 4;
    const int lc = lane & 15;
    const int bh = blockIdx.x, b = bh >> 3, h = bh & 7;

    const float* xqg = gXQ + (size_t)bh * (NMB * MBS * HD);
    const float* xkg = gXK + (size_t)bh * (NMB * MBS * HD);
    const float* xvg = gXV + (size_t)bh * (NMB * MBS * HD);
    const float* etg = gETA + (size_t)bh * (NMB * MBS * MBS);

    // W state: wave w owns rows [16w,16w+16) as 4 C-fragments + bf16 mirror
    f32x4 Wacc[4];
#pragma unroll
    for (int ct = 0; ct < 4; ++ct) {
#pragma unroll
        for (int r = 0; r < 4; ++r)
            Wacc[ct][r] = gW1[h * 4096 + (16 * w + 4 * gq + r) * 64 + 16 * ct + lc];
        U2S4 wp;
        wp.u[0] = pkbf(Wacc[ct][0], Wacc[ct][1]);
        wp.u[1] = pkbf(Wacc[ct][2], Wacc[ct][3]);
        *(short4_t*)&sWt[(16 * ct + lc) * 72 + 16 * w + 4 * gq] = wp.s;
    }
    // b1 state: register, wave w owns col 16w+lc
    float b1v = gB1[h * 64 + 16 * w + lc];

    const float4 gam = *(const float4*)&gLNW[h * 64 + dt * 4];
    const float4 bet = *(const float4*)&gLNB[h * 64 + dt * 4];
    const float ga[4] = {gam.x, gam.y, gam.z, gam.w};
    const float ba[4] = {bet.x, bet.y, bet.z, bet.w};
    float c1a[4], gba[4];
    float sc1 = 0.f;
#pragma unroll
    for (int c = 0; c < 4; ++c) {
        c1a[c] = ga[c] * ga[c];
        gba[c] = ga[c] * ba[c];
        sc1 += c1a[c];
    }
    sc1 = dpp16(sc1);

    // ---- load + stage minibatch 0 ----
    float4 pq = *(const float4*)&xqg[t * 4];
    float4 pk = *(const float4*)&xkg[t * 4];
    float4 pv = *(const float4*)&xvg[t * 4];
    float4 pe = make_float4(0.f, 0.f, 0.f, 0.f);
    if (t < 64) pe = *(const float4*)&etg[t * 4];

    { U2S4 u_; u_.u[0]=pkbf(pk.x,pk.y); u_.u[1]=pkbf(pk.z,pk.w);
      *(short4_t*)&bxk[s * 72 + dt * 4] = u_.s; }
    { U2S4 u_; u_.u[0]=pkbf(pq.x,pq.y); u_.u[1]=pkbf(pq.z,pq.w);
      *(short4_t*)&bxq[s * 72 + dt * 4] = u_.s; }
    if (t < 64) *(float4*)&sEta[0][t * 4] = pe;
    float t2c[4];
    {
        const float pva[4] = {pv.x, pv.y, pv.z, pv.w};
        const float pka_[4] = {pk.x, pk.y, pk.z, pk.w};
#pragma unroll
        for (int c = 0; c < 4; ++c)
            t2c[c] = fmaf(-ga[c], pva[c] - pka_[c], gba[c]);
    }
    float4 pkc = pk;        // xk(m) for THREAD1's sXKe
    float4 pq_out = pq;     // xq(m) for THREAD2(m)
    float4 pq_prev_out;     // xq(m-1) for deferred THREAD2

    __syncthreads();

#pragma unroll 1
    for (int m = 0; m < NMB; ++m) {
        const int p = m & 1;

        // ======== PHASE A: MFMA1 + E build (+ deferred THREAD2; prefetch m+1) ========
        if (m + 1 < NMB) {
            const size_t o = (size_t)(m + 1) * (MBS * HD) + t * 4;
            pq = *(const float4*)&xqg[o];
            pk = *(const float4*)&xkg[o];
            pv = *(const float4*)&xvg[o];
            if (t < 64) pe = *(const float4*)&etg[(size_t)(m + 1) * (MBS * MBS) + t * 4];
        }

        f32x4 z1a; z1a[0]=b1v; z1a[1]=b1v; z1a[2]=b1v; z1a[3]=b1v;
        f32x4 zqa = z1a;
        const short8 ak0 = *(const short8*)&bxk[lc * 72 + gq * 8];
        const short8 ak1 = *(const short8*)&bxk[lc * 72 + gq * 8 + 32];
        const short8 aq0 = *(const short8*)&bxq[lc * 72 + gq * 8];
        const short8 aq1 = *(const short8*)&bxq[lc * 72 + gq * 8 + 32];
        const short8 bw0 = *(const short8*)&sWt[(16 * w + lc) * 72 + gq * 8];
        const short8 bw1 = *(const short8*)&sWt[(16 * w + lc) * 72 + gq * 8 + 32];
        z1a = MFMA32(ak0, bw0, z1a); z1a = MFMA32(ak1, bw1, z1a);
        zqa = MFMA32(aq0, bw0, zqa); zqa = MFMA32(aq1, bw1, zqa);
#pragma unroll
        for (int r = 0; r < 4; ++r) sZ1[(4 * gq + r) * 68 + 16 * w + lc] = z1a[r];

        // wave 3: Attn = xq@xk^T (C-frag) -> -E written straight to sE
        if (w == 3) {
            f32x4 zz; zz[0]=0.f; zz[1]=0.f; zz[2]=0.f; zz[3]=0.f;
            zz = MFMA32(aq0, ak0, zz); zz = MFMA32(aq1, ak1, zz);
#pragma unroll
            for (int r = 0; r < 4; ++r) {
                const int row = 4 * gq + r;
                const float ev = sEta[p][row * 16 + lc];
                const float x = (lc <= row) ? -ev * (1.f + zz[r]) : 0.f;
                sE[row * 20 + lc] = bf16s(x);
            }
        }

        // deferred THREAD2 for step m-1 (off the W-recurrence chain)
        if (m > 0) {
            f32x4 zbr = *(f32x4*)&sZb[s * 68 + dt * 4];
            float T1 = 0.f, T2 = 0.f;
#pragma unroll
            for (int c = 0; c < 4; ++c) { T1 += zbr[c]; T2 = fmaf(zbr[c], zbr[c], T2); }
            T1 = dpp16(T1); T2 = dpp16(T2);
            const float mu2   = T1 * (1.f / 64.f);
            const float rstd2 = rsqrtf(T2 * (1.f / 64.f) - mu2 * mu2 + 1e-6f);
            const float pqa[4] = {pq_prev_out.x, pq_prev_out.y, pq_prev_out.z, pq_prev_out.w};
            float o[4];
#pragma unroll
            for (int c = 0; c < 4; ++c)
                o[c] = pqa[c] + fmaf(ga[c], (zbr[c] - mu2) * rstd2, ba[c]);
            const size_t oi = ((size_t)b * 4096 + (size_t)(m - 1) * 16 + s) * 512 + h * 64 + dt * 4;
            *(float4*)&gOUT[oi] = make_float4(o[0], o[1], o[2], o[3]);
        }
        bar();   // (C)

        // ======== PHASE B: LN-bwd (DPP 6-sum) -> g ; stage g^T, xke^T ========
        f32x4 z = *(f32x4*)&sZ1[s * 68 + dt * 4];
        float S1=0.f,S2=0.f,S3=0.f,S4=0.f,S5=0.f,S6=0.f;
#pragma unroll
        for (int c = 0; c < 4; ++c) {
            const float zc = z[c], c1z = c1a[c] * zc, t2 = t2c[c];
            S1 += zc;  S2 = fmaf(zc, zc, S2);
            S3 += c1z; S4 = fmaf(c1z, zc, S4);
            S5 += t2;  S6 = fmaf(t2, zc, S6);
        }
        S1 = dpp16(S1); S2 = dpp16(S2); S3 = dpp16(S3);
        S4 = dpp16(S4); S5 = dpp16(S5); S6 = dpp16(S6);
        const float mu   = S1 * (1.f / 64.f);
        const float rstd = rsqrtf(S2 * (1.f / 64.f) - mu * mu + 1e-6f);
        const float r1 = rstd * (S3 - mu * sc1) + S5;
        const float r2 = rstd * rstd * (S4 - 2.f * mu * S3 + mu * mu * sc1)
                       + rstd * (S6 - mu * S5);
        const float cf = rstd * (1.f / 64.f);
        float g[4];
#pragma unroll
        for (int c = 0; c < 4; ++c) {
            const float xh = (z[c] - mu) * rstd;
            const float gx = fmaf(c1a[c], xh, t2c[c]);
            g[c] = (fmaf(64.f, gx, -r1) - xh * r2) * cf;
        }

        const float le = sEta[p][240 + s];
        const int tb = (s >> 2) * 256 + (dt >> 2) * 64 + (s & 3) * 16 + (dt & 3) * 4;
        { U2S4 gp; gp.u[0]=pkbf(g[0],g[1]); gp.u[1]=pkbf(g[2],g[3]);
          *(short4_t*)&sGt[tb] = gp.s; }
        { U2S4 kp; kp.u[0]=pkbf(-le*pkc.x,-le*pkc.y); kp.u[1]=pkbf(-le*pkc.z,-le*pkc.w);
          *(short4_t*)&sXKe[tb] = kp.s; }
        bar();   // (D)

        // ======== PHASE C: MFMA2 K=16 (Z1_bar, W, b1) + STAGE(m+1) ========
        const unsigned gbase = (unsigned)(size_t)&sGt[0] + 512u * gq + 8u * lc;
        const unsigned kbase = (unsigned)(size_t)&sXKe[0] + 512u * gq + 128u * (unsigned)w + 8u * lc;
        short4_t bg0, bg1, bg2, bg3, aK;
        TR_READ(bg0, gbase, "0");
        TR_READ(bg1, gbase, "128");
        TR_READ(bg2, gbase, "256");
        TR_READ(bg3, gbase, "384");
        TR_READ(aK,  kbase, "0");
        const short4_t aE = *(const short4_t*)&sE[lc * 20 + gq * 4];
        // aL: A[row][k=4gq+i] = -le[4gq+i] (broadcast read)
        const f32x4 lv = *(const f32x4*)&sEta[p][240 + 4 * gq];
        U2S4 aL;
        aL.u[0] = pkbf(-lv[0], -lv[1]);
        aL.u[1] = pkbf(-lv[2], -lv[3]);
        asm volatile("s_waitcnt lgkmcnt(0)" ::: "memory");
        __builtin_amdgcn_sched_barrier(0);

        // wave-uniform select of this wave's g n-tile
        short4_t bgw = bg0;
        if (w == 1) bgw = bg1;
        else if (w == 2) bgw = bg2;
        else if (w == 3) bgw = bg3;

        f32x4 zb = MFMA16(aE, bgw, zqa);
#pragma unroll
        for (int r = 0; r < 4; ++r) sZb[(4 * gq + r) * 68 + 16 * w + lc] = zb[r];

        Wacc[0] = MFMA16(aK, bg0, Wacc[0]);
        Wacc[1] = MFMA16(aK, bg1, Wacc[1]);
        Wacc[2] = MFMA16(aK, bg2, Wacc[2]);
        Wacc[3] = MFMA16(aK, bg3, Wacc[3]);
        // b1 update: d0 = (-le) @ g
        {
            f32x4 d0; d0[0]=0.f; d0[1]=0.f; d0[2]=0.f; d0[3]=0.f;
            d0 = MFMA16(aL.s, bgw, d0);
            b1v += d0[0];
        }
#pragma unroll
        for (int ct = 0; ct < 4; ++ct) {
            U2S4 wp;
            wp.u[0] = pkbf(Wacc[ct][0], Wacc[ct][1]);
            wp.u[1] = pkbf(Wacc[ct][2], Wacc[ct][3]);
            *(short4_t*)&sWt[(16 * ct + lc) * 72 + 16 * w + 4 * gq] = wp.s;
        }

        // STAGE(m+1): bxk/bxq/sEta[p^1]/t2 from prefetched regs
        if (m + 1 < NMB) {
            { U2S4 u_; u_.u[0]=pkbf(pk.x,pk.y); u_.u[1]=pkbf(pk.z,pk.w);
              *(short4_t*)&bxk[s * 72 + dt * 4] = u_.s; }
            { U2S4 u_; u_.u[0]=pkbf(pq.x,pq.y); u_.u[1]=pkbf(pq.z,pq.w);
              *(short4_t*)&bxq[s * 72 + dt * 4] = u_.s; }
            if (t < 64) *(float4*)&sEta[p ^ 1][t * 4] = pe;
#pragma unroll
            for (int c = 0; c < 4; ++c) {
                const float pva[4] = {pv.x, pv.y, pv.z, pv.w};
                const float pka_[4] = {pk.x, pk.y, pk.z, pk.w};
                t2c[c] = fmaf(-ga[c], pva[c] - pka_[c], gba[c]);
            }
            pkc = pk;
        }
        pq_prev_out = pq_out;
        pq_out = pq;
        bar();   // (E)
    }

    // epilogue: deferred THREAD2 for m = NMB-1
    {
        f32x4 zbr = *(f32x4*)&sZb[s * 68 + dt * 4];
        float T1 = 0.f, T2 = 0.f;
#pragma unroll
        for (int c = 0; c < 4; ++c) { T1 += zbr[c]; T2 = fmaf(zbr[c], zbr[c], T2); }
        T1 = dpp16(T1); T2 = dpp16(T2);
        const float mu2   = T1 * (1.f / 64.f);
        const float rstd2 = rsqrtf(T2 * (1.f / 64.f) - mu2 * mu2 + 1e-6f);
        const float pqa[4] = {pq_prev_out.x, pq_prev_out.y, pq_prev_out.z, pq_prev_out.w};
        float o[4];
#pragma unroll
        for (int c = 0; c < 4; ++c)
            o[c] = pqa[c] + fmaf(ga[c], (zbr[c] - mu2) * rstd2, ba[c]);
        const size_t oi = ((size_t)b * 4096 + (size_t)(NMB - 1) * 16 + s) * 512 + h * 64 + dt * 4;
        *(float4*)&gOUT[oi] = make_float4(o[0], o[1], o[2], o[3]);
    }
}

extern "C" void kernel_launch(void* const* d_in, const int* in_sizes, int n_in,
                              void* d_out, int out_size, void* d_ws, size_t ws_size,
                              hipStream_t stream) {
    const float* XQ  = (const float*)d_in[0];
    const float* XK  = (const float*)d_in[1];
    const float* XV  = (const float*)d_in[2];
    const float* ETA = (const float*)d_in[3];
    const float* W1  = (const float*)d_in[4];
    const float* B1  = (const float*)d_in[5];
    const float* LNW = (const float*)d_in[6];
    const float* LNB = (const float*)d_in[7];
    float* OUT = (float*)d_out;

    const int n_chains = in_sizes[0] / (NMB * MBS * HD);   // B*nh = 64
    ttt_scan<<<n_chains, 256, 0, stream>>>(XQ, XK, XV, ETA, W1, B1, LNW, LNB, OUT);
}

// Round 11
// 374.391 us; speedup vs baseline: 1.3077x; 1.0009x over previous
//
#include <hip/hip_runtime.h>
#include <hip/hip_bf16.h>

typedef __attribute__((ext_vector_type(8))) short short8;
typedef __attribute__((ext_vector_type(4))) short short4_t;
typedef __attribute__((ext_vector_type(4))) float f32x4;

constexpr int MBS = 16, HD = 64, NMB = 256;

#define MFMA32(a, b, c) __builtin_amdgcn_mfma_f32_16x16x32_bf16(a, b, c, 0, 0, 0)

#if __has_builtin(__builtin_amdgcn_mfma_f32_16x16x16bf16_1k)
#define MFMA16(a, b, c) __builtin_amdgcn_mfma_f32_16x16x16bf16_1k(a, b, c, 0, 0, 0)
#else
__device__ inline f32x4 mfma16_asm(short4_t a, short4_t b, f32x4 c) {
    asm volatile("v_mfma_f32_16x16x16_bf16 %0, %1, %2, %0\n\ts_nop 7\n\ts_nop 7"
                 : "+v"(c) : "v"(a), "v"(b));
    return c;
}
#define MFMA16(a, b, c) mfma16_asm(a, b, c)
#endif

#define TR_READ(dst, addr, IMM) \
    asm volatile("ds_read_b64_tr_b16 %0, %1 offset:" IMM : "=&v"(dst) : "v"(addr) : "memory")

union U2S4 { unsigned u[2]; short4_t s; };
union FI { float f; int i; };

__device__ inline unsigned pkbf(float a, float b) {
    union { __hip_bfloat162 h; unsigned u; } c;
    c.h = __float22bfloat162_rn(make_float2(a, b));
    return c.u;
}
__device__ inline short bf16s(float x) { return (short)(pkbf(x, 0.f) & 0xffffu); }
// all-VALU 16-lane sum reduce: quad_perm xor1, xor2, then row_ror 4, 8
__device__ inline float dpp16(float x) {
    FI v; v.f = x; FI t;
    t.i = __builtin_amdgcn_update_dpp(0, v.i, 0xB1, 0xf, 0xf, true);  v.f += t.f;
    t.i = __builtin_amdgcn_update_dpp(0, v.i, 0x4E, 0xf, 0xf, true);  v.f += t.f;
    t.i = __builtin_amdgcn_update_dpp(0, v.i, 0x124, 0xf, 0xf, true); v.f += t.f;
    t.i = __builtin_amdgcn_update_dpp(0, v.i, 0x128, 0xf, 0xf, true); v.f += t.f;
    return v.f;
}
// raw barrier: LDS writes visible, global loads stay in flight
__device__ inline void bar() {
    __builtin_amdgcn_sched_barrier(0);
    asm volatile("s_waitcnt lgkmcnt(0)" ::: "memory");
    __builtin_amdgcn_s_barrier();
    __builtin_amdgcn_sched_barrier(0);
}

__global__ __launch_bounds__(512) void ttt_scan(
    const float* __restrict__ gXQ, const float* __restrict__ gXK,
    const float* __restrict__ gXV, const float* __restrict__ gETA,
    const float* __restrict__ gW1, const float* __restrict__ gB1,
    const float* __restrict__ gLNW, const float* __restrict__ gLNB,
    float* __restrict__ gOUT)
{
    __shared__ __align__(16) short sWt[64 * 72];   // W^T bf16 [n][k], stride 72
    __shared__ __align__(16) short bxk[16 * 72];
    __shared__ __align__(16) short bxq[16 * 72];
    __shared__ __align__(16) short sGt[1024];      // g, K=16 4x16 tiles [jblk][nblk]
    __shared__ __align__(16) short sXKe[1024];     // -le*xk, same tiling
    __shared__ __align__(16) short sE[16 * 20];    // -E [r][j], row stride 20
    __shared__ __align__(16) float sZ1[16 * 68];
    __shared__ __align__(16) float sZb[16 * 68];
    __shared__ __align__(16) float sEta[2][256];   // parity-buffered

    const int t  = threadIdx.x;
    const bool prod = (t < 256);       // waves 0-3: W-recurrence; 4-7: off-chain
    const int t4 = t & 255;
    const int s  = t4 >> 4;
    const int dt = t4 & 15;
    const int lane = t4 & 63;
    const int w  = t4 >> 6;            // group-local wave 0..3
    const int gq = lane >> 4;
    const int lc = lane & 15;
    const int bh = blockIdx.x, b = bh >> 3, h = bh & 7;

    const float* xqg = gXQ + (size_t)bh * (NMB * MBS * HD);
    const float* xkg = gXK + (size_t)bh * (NMB * MBS * HD);
    const float* xvg = gXV + (size_t)bh * (NMB * MBS * HD);
    const float* etg = gETA + (size_t)bh * (NMB * MBS * MBS);

    // W state (producers): wave w owns rows [16w,16w+16) as 4 C-fragments + bf16 mirror
    f32x4 Wacc[4];
    if (prod) {
#pragma unroll
        for (int ct = 0; ct < 4; ++ct) {
#pragma unroll
            for (int r = 0; r < 4; ++r)
                Wacc[ct][r] = gW1[h * 4096 + (16 * w + 4 * gq + r) * 64 + 16 * ct + lc];
            U2S4 wp;
            wp.u[0] = pkbf(Wacc[ct][0], Wacc[ct][1]);
            wp.u[1] = pkbf(Wacc[ct][2], Wacc[ct][3]);
            *(short4_t*)&sWt[(16 * ct + lc) * 72 + 16 * w + 4 * gq] = wp.s;
        }
    }
    // b1 state: both groups keep identical replicas (col 16w+lc)
    float b1v = gB1[h * 64 + 16 * w + lc];

    const float4 gam = *(const float4*)&gLNW[h * 64 + dt * 4];
    const float4 bet = *(const float4*)&gLNB[h * 64 + dt * 4];
    const float ga[4] = {gam.x, gam.y, gam.z, gam.w};
    const float ba[4] = {bet.x, bet.y, bet.z, bet.w};
    float c1a[4], gba[4];
    float sc1 = 0.f;
#pragma unroll
    for (int c = 0; c < 4; ++c) {
        c1a[c] = ga[c] * ga[c];
        gba[c] = ga[c] * ba[c];
        sc1 += c1a[c];
    }
    sc1 = dpp16(sc1);

    // ---- pre-loop loads + initial stage (minibatch 0) ----
    float4 pk_c, pv_c, pk_n, pv_n;                 // producers
    float4 pq_c, pq_n, pq_prev, pkb_n, pe_n;       // consumers
    if (prod) {
        pk_c = *(const float4*)&xkg[t4 * 4];
        pv_c = *(const float4*)&xvg[t4 * 4];
    } else {
        pq_c = *(const float4*)&xqg[t4 * 4];
        float4 k0 = *(const float4*)&xkg[t4 * 4];
        { U2S4 u_; u_.u[0]=pkbf(k0.x,k0.y); u_.u[1]=pkbf(k0.z,k0.w);
          *(short4_t*)&bxk[s * 72 + dt * 4] = u_.s; }
        { U2S4 u_; u_.u[0]=pkbf(pq_c.x,pq_c.y); u_.u[1]=pkbf(pq_c.z,pq_c.w);
          *(short4_t*)&bxq[s * 72 + dt * 4] = u_.s; }
        if (t4 < 64) {
            float4 e0 = *(const float4*)&etg[t4 * 4];
            *(float4*)&sEta[0][t4 * 4] = e0;
        }
    }
    __syncthreads();

#pragma unroll 1
    for (int m = 0; m < NMB; ++m) {
        const int p = m & 1;
        f32x4 zqa, zz;     // consumer regs (persist A->C / A->B)

        // ======== PHASE A ========
        if (m + 1 < NMB) {
            const size_t o = (size_t)(m + 1) * (MBS * HD) + t4 * 4;
            if (prod) {
                pk_n = *(const float4*)&xkg[o];
                pv_n = *(const float4*)&xvg[o];
            } else {
                pq_n  = *(const float4*)&xqg[o];
                pkb_n = *(const float4*)&xkg[o];
                if (t4 < 64)
                    pe_n = *(const float4*)&etg[(size_t)(m + 1) * (MBS * MBS) + t4 * 4];
            }
        }
        if (prod) {
            // Z1 n-tile w = xk @ W + b1
            f32x4 z1a; z1a[0]=b1v; z1a[1]=b1v; z1a[2]=b1v; z1a[3]=b1v;
            const short8 ak0 = *(const short8*)&bxk[lc * 72 + gq * 8];
            const short8 ak1 = *(const short8*)&bxk[lc * 72 + gq * 8 + 32];
            const short8 bw0 = *(const short8*)&sWt[(16 * w + lc) * 72 + gq * 8];
            const short8 bw1 = *(const short8*)&sWt[(16 * w + lc) * 72 + gq * 8 + 32];
            z1a = MFMA32(ak0, bw0, z1a); z1a = MFMA32(ak1, bw1, z1a);
#pragma unroll
            for (int r = 0; r < 4; ++r) sZ1[(4 * gq + r) * 68 + 16 * w + lc] = z1a[r];
        } else {
            // Zq n-tile w = xq @ W + b1 ; wave 3 also Attn C-frag
            zqa[0]=b1v; zqa[1]=b1v; zqa[2]=b1v; zqa[3]=b1v;
            const short8 aq0 = *(const short8*)&bxq[lc * 72 + gq * 8];
            const short8 aq1 = *(const short8*)&bxq[lc * 72 + gq * 8 + 32];
            const short8 bw0 = *(const short8*)&sWt[(16 * w + lc) * 72 + gq * 8];
            const short8 bw1 = *(const short8*)&sWt[(16 * w + lc) * 72 + gq * 8 + 32];
            zqa = MFMA32(aq0, bw0, zqa); zqa = MFMA32(aq1, bw1, zqa);
            if (w == 3) {
                const short8 ak0 = *(const short8*)&bxk[lc * 72 + gq * 8];
                const short8 ak1 = *(const short8*)&bxk[lc * 72 + gq * 8 + 32];
                zz[0]=0.f; zz[1]=0.f; zz[2]=0.f; zz[3]=0.f;
                zz = MFMA32(aq0, ak0, zz); zz = MFMA32(aq1, ak1, zz);
            }
            // deferred LN-fwd + output for step m-1
            if (m > 0) {
                f32x4 zbr = *(f32x4*)&sZb[s * 68 + dt * 4];
                float T1 = 0.f, T2 = 0.f;
#pragma unroll
                for (int c = 0; c < 4; ++c) { T1 += zbr[c]; T2 = fmaf(zbr[c], zbr[c], T2); }
                T1 = dpp16(T1); T2 = dpp16(T2);
                const float mu2   = T1 * (1.f / 64.f);
                const float rstd2 = rsqrtf(T2 * (1.f / 64.f) - mu2 * mu2 + 1e-6f);
                const float pqa[4] = {pq_prev.x, pq_prev.y, pq_prev.z, pq_prev.w};
                float o[4];
#pragma unroll
                for (int c = 0; c < 4; ++c)
                    o[c] = pqa[c] + fmaf(ga[c], (zbr[c] - mu2) * rstd2, ba[c]);
                const size_t oi = ((size_t)b * 4096 + (size_t)(m - 1) * 16 + s) * 512 + h * 64 + dt * 4;
                *(float4*)&gOUT[oi] = make_float4(o[0], o[1], o[2], o[3]);
            }
        }
        bar();   // (1) sZ1 visible

        // ======== PHASE B ========
        if (prod) {
            float t2c[4];
            {
                const float pva[4] = {pv_c.x, pv_c.y, pv_c.z, pv_c.w};
                const float pka_[4] = {pk_c.x, pk_c.y, pk_c.z, pk_c.w};
#pragma unroll
                for (int c = 0; c < 4; ++c)
                    t2c[c] = fmaf(-ga[c], pva[c] - pka_[c], gba[c]);
            }
            f32x4 z = *(f32x4*)&sZ1[s * 68 + dt * 4];
            float S1=0.f,S2=0.f,S3=0.f,S4=0.f,S5=0.f,S6=0.f;
#pragma unroll
            for (int c = 0; c < 4; ++c) {
                const float zc = z[c], c1z = c1a[c] * zc, t2 = t2c[c];
                S1 += zc;  S2 = fmaf(zc, zc, S2);
                S3 += c1z; S4 = fmaf(c1z, zc, S4);
                S5 += t2;  S6 = fmaf(t2, zc, S6);
            }
            S1 = dpp16(S1); S2 = dpp16(S2); S3 = dpp16(S3);
            S4 = dpp16(S4); S5 = dpp16(S5); S6 = dpp16(S6);
            const float mu   = S1 * (1.f / 64.f);
            const float rstd = rsqrtf(S2 * (1.f / 64.f) - mu * mu + 1e-6f);
            const float r1 = rstd * (S3 - mu * sc1) + S5;
            const float r2 = rstd * rstd * (S4 - 2.f * mu * S3 + mu * mu * sc1)
                           + rstd * (S6 - mu * S5);
            const float cf = rstd * (1.f / 64.f);
            float g[4];
#pragma unroll
            for (int c = 0; c < 4; ++c) {
                const float xh = (z[c] - mu) * rstd;
                const float gx = fmaf(c1a[c], xh, t2c[c]);
                g[c] = (fmaf(64.f, gx, -r1) - xh * r2) * cf;
            }
            const float le = sEta[p][240 + s];
            const int tb = (s >> 2) * 256 + (dt >> 2) * 64 + (s & 3) * 16 + (dt & 3) * 4;
            { U2S4 gp; gp.u[0]=pkbf(g[0],g[1]); gp.u[1]=pkbf(g[2],g[3]);
              *(short4_t*)&sGt[tb] = gp.s; }
            { U2S4 kp; kp.u[0]=pkbf(-le*pk_c.x,-le*pk_c.y); kp.u[1]=pkbf(-le*pk_c.z,-le*pk_c.w);
              *(short4_t*)&sXKe[tb] = kp.s; }
            pk_c = pk_n; pv_c = pv_n;
        } else {
            // stage m+1 into bxk/bxq/sEta[p^1]
            if (m + 1 < NMB) {
                { U2S4 u_; u_.u[0]=pkbf(pkb_n.x,pkb_n.y); u_.u[1]=pkbf(pkb_n.z,pkb_n.w);
                  *(short4_t*)&bxk[s * 72 + dt * 4] = u_.s; }
                { U2S4 u_; u_.u[0]=pkbf(pq_n.x,pq_n.y); u_.u[1]=pkbf(pq_n.z,pq_n.w);
                  *(short4_t*)&bxq[s * 72 + dt * 4] = u_.s; }
                if (t4 < 64) *(float4*)&sEta[p ^ 1][t4 * 4] = pe_n;
            }
            // wave 3: build -E from Attn C-frag
            if (w == 3) {
#pragma unroll
                for (int r = 0; r < 4; ++r) {
                    const int row = 4 * gq + r;
                    const float ev = sEta[p][row * 16 + lc];
                    const float x = (lc <= row) ? -ev * (1.f + zz[r]) : 0.f;
                    sE[row * 20 + lc] = bf16s(x);
                }
            }
            pq_prev = pq_c; pq_c = pq_n;
        }
        bar();   // (2) sGt/sXKe/sE visible

        // ======== PHASE C ========
        const unsigned gbase = (unsigned)(size_t)&sGt[0] + 512u * gq + 8u * lc;
        const f32x4 lv = *(const f32x4*)&sEta[p][240 + 4 * gq];
        U2S4 aL;
        aL.u[0] = pkbf(-lv[0], -lv[1]);
        aL.u[1] = pkbf(-lv[2], -lv[3]);
        if (prod) {
            const unsigned kbase = (unsigned)(size_t)&sXKe[0] + 512u * gq + 128u * (unsigned)w + 8u * lc;
            short4_t bg0, bg1, bg2, bg3, aK;
            TR_READ(bg0, gbase, "0");
            TR_READ(bg1, gbase, "128");
            TR_READ(bg2, gbase, "256");
            TR_READ(bg3, gbase, "384");
            TR_READ(aK,  kbase, "0");
            asm volatile("s_waitcnt lgkmcnt(0)" ::: "memory");
            __builtin_amdgcn_sched_barrier(0);

            Wacc[0] = MFMA16(aK, bg0, Wacc[0]);
            Wacc[1] = MFMA16(aK, bg1, Wacc[1]);
            Wacc[2] = MFMA16(aK, bg2, Wacc[2]);
            Wacc[3] = MFMA16(aK, bg3, Wacc[3]);
            short4_t bgw = bg0;
            if (w == 1) bgw = bg1;
            else if (w == 2) bgw = bg2;
            else if (w == 3) bgw = bg3;
            f32x4 d0; d0[0]=0.f; d0[1]=0.f; d0[2]=0.f; d0[3]=0.f;
            d0 = MFMA16(aL.s, bgw, d0);
            b1v += d0[0];
#pragma unroll
            for (int ct = 0; ct < 4; ++ct) {
                U2S4 wp;
                wp.u[0] = pkbf(Wacc[ct][0], Wacc[ct][1]);
                wp.u[1] = pkbf(Wacc[ct][2], Wacc[ct][3]);
                *(short4_t*)&sWt[(16 * ct + lc) * 72 + 16 * w + 4 * gq] = wp.s;
            }
        } else {
            short4_t bgw;
            const unsigned gbw = gbase + 128u * (unsigned)w;
            TR_READ(bgw, gbw, "0");
            const short4_t aE = *(const short4_t*)&sE[lc * 20 + gq * 4];
            asm volatile("s_waitcnt lgkmcnt(0)" ::: "memory");
            __builtin_amdgcn_sched_barrier(0);

            f32x4 zb = MFMA16(aE, bgw, zqa);
#pragma unroll
            for (int r = 0; r < 4; ++r) sZb[(4 * gq + r) * 68 + 16 * w + lc] = zb[r];
            f32x4 d0; d0[0]=0.f; d0[1]=0.f; d0[2]=0.f; d0[3]=0.f;
            d0 = MFMA16(aL.s, bgw, d0);
            b1v += d0[0];
        }
        bar();   // (3) sWt/sZb visible
    }

    // epilogue: deferred output for m = NMB-1 (consumers)
    if (!prod) {
        f32x4 zbr = *(f32x4*)&sZb[s * 68 + dt * 4];
        float T1 = 0.f, T2 = 0.f;
#pragma unroll
        for (int c = 0; c < 4; ++c) { T1 += zbr[c]; T2 = fmaf(zbr[c], zbr[c], T2); }
        T1 = dpp16(T1); T2 = dpp16(T2);
        const float mu2   = T1 * (1.f / 64.f);
        const float rstd2 = rsqrtf(T2 * (1.f / 64.f) - mu2 * mu2 + 1e-6f);
        const float pqa[4] = {pq_prev.x, pq_prev.y, pq_prev.z, pq_prev.w};
        float o[4];
#pragma unroll
        for (int c = 0; c < 4; ++c)
            o[c] = pqa[c] + fmaf(ga[c], (zbr[c] - mu2) * rstd2, ba[c]);
        const size_t oi = ((size_t)b * 4096 + (size_t)(NMB - 1) * 16 + s) * 512 + h * 64 + dt * 4;
        *(float4*)&gOUT[oi] = make_float4(o[0], o[1], o[2], o[3]);
    }
}

extern "C" void kernel_launch(void* const* d_in, const int* in_sizes, int n_in,
                              void* d_out, int out_size, void* d_ws, size_t ws_size,
                              hipStream_t stream) {
    const float* XQ  = (const float*)d_in[0];
    const float* XK  = (const float*)d_in[1];
    const float* XV  = (const float*)d_in[2];
    const float* ETA = (const float*)d_in[3];
    const float* W1  = (const float*)d_in[4];
    const float* B1  = (const float*)d_in[5];
    const float* LNW = (const float*)d_in[6];
    const float* LNB = (const float*)d_in[7];
    float* OUT = (float*)d_out;

    const int n_chains = in_sizes[0] / (NMB * MBS * HD);   // B*nh = 64
    ttt_scan<<<n_chains, 512, 0, stream>>>(XQ, XK, XV, ETA, W1, B1, LNW, LNB, OUT);
}